// Round 1
// baseline (12089.131 us; speedup 1.0000x reference)
//
#include <hip/hip_runtime.h>
#include <hip/hip_bf16.h>
#include <math.h>

#define BB 256
#define TT 128
#define DD 128
#define HH 1024
#define G4 4096
#define TOUT 127
#define OSZ (BB * TOUT * DD)

typedef __bf16 bf16x8 __attribute__((ext_vector_type(8)));
typedef float f32x4 __attribute__((ext_vector_type(4)));
typedef unsigned short u16;

__device__ inline u16 f2bf(float f) {
    union { float f; unsigned u; } v; v.f = f;
    unsigned r = v.u + 0x7FFFu + ((v.u >> 16) & 1u);
    return (u16)(r >> 16);
}
__device__ inline float fsig(float x) { return __fdividef(1.0f, 1.0f + __expf(-x)); }
__device__ inline float ftanh(float x) { return __fdividef(2.0f, 1.0f + __expf(-2.0f * x)) - 1.0f; }

// Accumulate a 32x32 (per-wave) tile of C += A(MxK) * B^T (B is NxK row-major).
// A-frag: lane reads A[m_base + (lane&15)][k + (lane>>4)*8 .. +7]  (16B contiguous)
// B-frag: lane reads B[n_base + (lane&15)][k + (lane>>4)*8 .. +7]  (16B contiguous)
__device__ inline void gemm_seg(const u16* __restrict__ A, int lda,
                                const u16* __restrict__ Bm, int ldb, int K,
                                int m_base, int n_base, int lane, f32x4 acc[2][2]) {
    const int r = lane & 15, q = lane >> 4;
    const u16* a0 = A + (m_base + r) * lda + q * 8;
    const u16* a1 = a0 + 16 * lda;
    const u16* b0 = Bm + (n_base + r) * ldb + q * 8;
    const u16* b1 = b0 + 16 * ldb;
#pragma unroll 4
    for (int k = 0; k < K; k += 32) {
        bf16x8 av0 = *(const bf16x8*)(a0 + k);
        bf16x8 av1 = *(const bf16x8*)(a1 + k);
        bf16x8 bv0 = *(const bf16x8*)(b0 + k);
        bf16x8 bv1 = *(const bf16x8*)(b1 + k);
        acc[0][0] = __builtin_amdgcn_mfma_f32_16x16x32_bf16(av0, bv0, acc[0][0], 0, 0, 0);
        acc[0][1] = __builtin_amdgcn_mfma_f32_16x16x32_bf16(av0, bv1, acc[0][1], 0, 0, 0);
        acc[1][0] = __builtin_amdgcn_mfma_f32_16x16x32_bf16(av1, bv0, acc[1][0], 0, 0, 0);
        acc[1][1] = __builtin_amdgcn_mfma_f32_16x16x32_bf16(av1, bv1, acc[1][1], 0, 0, 0);
    }
}

// Gates GEMM (256 x 4096, K = 128 + 1024) with fused LSTM cell epilogue.
// Weights are gate-interleaved: row (4*j + g) = original row (g*H + j), so a
// 16-col C tile holds i,f,g,o in lanes differing only in (lane&3).
__global__ __launch_bounds__(256) void k_lstm(
    const u16* __restrict__ inp, const u16* __restrict__ hin,
    const u16* __restrict__ Wx, const u16* __restrict__ Wh,
    const float* __restrict__ bias, float* __restrict__ c, u16* __restrict__ hout)
{
    const int tid = threadIdx.x;
    const int lane = tid & 63, wave = tid >> 6;
    const int m_base = blockIdx.y * 64 + (wave >> 1) * 32;
    const int n_base = blockIdx.x * 64 + (wave & 1) * 32;
    f32x4 acc[2][2] = {};
    gemm_seg(inp, DD, Wx, DD, DD, m_base, n_base, lane, acc);
    gemm_seg(hin, HH, Wh, HH, HH, m_base, n_base, lane, acc);

    const int col = lane & 15, row4 = (lane >> 4) * 4, g0 = lane & 3;
#pragma unroll
    for (int mi = 0; mi < 2; ++mi)
#pragma unroll
    for (int ni = 0; ni < 2; ++ni) {
        const int n = n_base + ni * 16 + col;
        const float bv = bias[n];
        const int j = n >> 2;  // same for all 4 lanes of the quad
#pragma unroll
        for (int rr = 0; rr < 4; ++rr) {
            float v = acc[mi][ni][rr] + bv;
            float v1 = __shfl_xor(v, 1);
            float v2 = __shfl_xor(v, 2);
            float v3 = __shfl_xor(v, 3);
            if (g0 == 0) {  // lane holds gate i; v1=f, v2=g, v3=o
                const int m = m_base + mi * 16 + row4 + rr;
                float cprev = c[m * HH + j];
                float cy = cprev * fsig(v1) + fsig(v) * ftanh(v2);
                float hy = fsig(v3) * ftanh(cy);
                c[m * HH + j] = cy;
                hout[m * HH + j] = f2bf(hy);
            }
        }
    }
}

// mu = hn @ fs_w^T + fs_b (256x128, K=1024); epilogue: mask/reg/z outputs,
// p-LSTM input (mask * x[:,t+1,:]), mask scratch.
__global__ __launch_bounds__(256) void k_mu(
    const u16* __restrict__ h, const u16* __restrict__ W, const float* __restrict__ bias,
    const float* __restrict__ x, int t,
    float* __restrict__ o_mask, float* __restrict__ o_reg, float* __restrict__ o_mu,
    float* __restrict__ o_prob, float* __restrict__ o_z,
    u16* __restrict__ xin, float* __restrict__ mbuf)
{
    const int tid = threadIdx.x;
    const int lane = tid & 63, wave = tid >> 6;
    const int m_base = blockIdx.y * 64 + (wave >> 1) * 32;
    const int n_base = blockIdx.x * 64 + (wave & 1) * 32;
    f32x4 acc[2][2] = {};
    gemm_seg(h, HH, W, HH, HH, m_base, n_base, lane, acc);

    const int col = lane & 15, row4 = (lane >> 4) * 4;
#pragma unroll
    for (int mi = 0; mi < 2; ++mi)
#pragma unroll
    for (int ni = 0; ni < 2; ++ni) {
        const int n = n_base + ni * 16 + col;
        const float bv = bias[n];
#pragma unroll
        for (int rr = 0; rr < 4; ++rr) {
            const int m = m_base + mi * 16 + row4 + rr;
            float mu = acc[mi][ni][rr] + bv;
            float mask = fminf(fmaxf(mu + 0.5f, 0.0f), 1.0f);
            float reg = 0.5f * (1.0f + erff((mu + 0.5f) * 1.41421356237f));
            const int o = m * (TOUT * DD) + t * DD + n;
            o_mask[o] = mask;
            o_reg[o]  = reg;
            o_mu[o]   = mu;
            o_prob[o] = reg;
            o_z[o]    = mu;
            float xv = x[m * (TT * DD) + (t + 1) * DD + n];
            xin[m * DD + n]  = f2bf(mask * xv);
            mbuf[m * DD + n] = mask;
        }
    }
}

// xhat = hn2 @ p_fc_w^T + b (256x256, K=1024); epilogue: xhat0/xhat1 outputs,
// next-step s-LSTM input = mask*x[:,t+1,:] + (1-mask)*xhat0.
__global__ __launch_bounds__(256) void k_fc(
    const u16* __restrict__ h2, const u16* __restrict__ W, const float* __restrict__ bias,
    const float* __restrict__ x, int t, const float* __restrict__ mbuf,
    float* __restrict__ o_x0, float* __restrict__ o_x1, u16* __restrict__ inp_next)
{
    const int tid = threadIdx.x;
    const int lane = tid & 63, wave = tid >> 6;
    const int m_base = blockIdx.y * 64 + (wave >> 1) * 32;
    const int n_base = blockIdx.x * 64 + (wave & 1) * 32;
    f32x4 acc[2][2] = {};
    gemm_seg(h2, HH, W, HH, HH, m_base, n_base, lane, acc);

    const int col = lane & 15, row4 = (lane >> 4) * 4;
#pragma unroll
    for (int mi = 0; mi < 2; ++mi)
#pragma unroll
    for (int ni = 0; ni < 2; ++ni) {
        const int n = n_base + ni * 16 + col;
        const float bv = bias[n];
#pragma unroll
        for (int rr = 0; rr < 4; ++rr) {
            const int m = m_base + mi * 16 + row4 + rr;
            float v = acc[mi][ni][rr] + bv;
            if (n < DD) {
                o_x0[m * (TOUT * DD) + t * DD + n] = v;
                float mk = mbuf[m * DD + n];
                float xv = x[m * (TT * DD) + (t + 1) * DD + n];
                inp_next[m * DD + n] = f2bf(mk * xv + (1.0f - mk) * v);
            } else {
                o_x1[m * (TOUT * DD) + t * DD + (n - DD)] = v;
            }
        }
    }
}

__global__ void k_cvt(const float* __restrict__ src, u16* __restrict__ dst, int n) {
    int i = blockIdx.x * blockDim.x + threadIdx.x;
    if (i < n) dst[i] = f2bf(src[i]);
}
// dst[r][k] = src[gate-deinterleaved row][k]; new row r = 4*j + g, old row = g*H + j.
__global__ void k_cvt_gates(const float* __restrict__ src, u16* __restrict__ dst, int kshift, int n) {
    int i = blockIdx.x * blockDim.x + threadIdx.x;
    if (i >= n) return;
    int r = i >> kshift, k = i & ((1 << kshift) - 1);
    int oldr = ((r & 3) << 10) + (r >> 2);
    dst[i] = f2bf(src[(oldr << kshift) + k]);
}
__global__ void k_bias2(const float* __restrict__ bx, const float* __restrict__ bh, float* __restrict__ dst) {
    int r = blockIdx.x * blockDim.x + threadIdx.x;
    if (r < G4) {
        int o = ((r & 3) << 10) + (r >> 2);
        dst[r] = bx[o] + bh[o];
    }
}
__global__ void k_init(const float* __restrict__ x, u16* __restrict__ inp,
                       u16* __restrict__ hs, u16* __restrict__ hp,
                       float* __restrict__ cs, float* __restrict__ cp) {
    int i = blockIdx.x * blockDim.x + threadIdx.x;
    if (i < BB * HH) { hs[i] = 0; hp[i] = 0; cs[i] = 0.f; cp[i] = 0.f; }
    if (i < BB * DD) {
        int b = i >> 7, d = i & 127;
        inp[i] = f2bf(x[b * (TT * DD) + d]);  // mask0=1, xhat0_prev=0 -> inp = x[:,0,:]
    }
}

extern "C" void kernel_launch(void* const* d_in, const int* in_sizes, int n_in,
                              void* d_out, int out_size, void* d_ws, size_t ws_size,
                              hipStream_t stream) {
    const float* x        = (const float*)d_in[0];
    const float* s_x2h_w  = (const float*)d_in[1];
    const float* s_x2h_b  = (const float*)d_in[2];
    const float* s_h2h_w  = (const float*)d_in[3];
    const float* s_h2h_b  = (const float*)d_in[4];
    const float* p_x2h_w  = (const float*)d_in[5];
    const float* p_x2h_b  = (const float*)d_in[6];
    const float* p_h2h_w  = (const float*)d_in[7];
    const float* p_h2h_b  = (const float*)d_in[8];
    const float* p_fc_w   = (const float*)d_in[9];
    const float* p_fc_b   = (const float*)d_in[10];
    const float* fs_w     = (const float*)d_in[11];
    const float* fs_b     = (const float*)d_in[12];

    float* out = (float*)d_out;
    float* o_mask = out + 0 * (size_t)OSZ;
    float* o_x0   = out + 1 * (size_t)OSZ;
    float* o_x1   = out + 2 * (size_t)OSZ;
    float* o_reg  = out + 3 * (size_t)OSZ;
    float* o_mu   = out + 4 * (size_t)OSZ;
    float* o_prob = out + 5 * (size_t)OSZ;
    float* o_z    = out + 6 * (size_t)OSZ;

    char* ws = (char*)d_ws;
    size_t off = 0;
    auto alloc = [&](size_t bytes) { void* p = ws + off; off += (bytes + 255) & ~(size_t)255; return p; };
    u16*   wxs  = (u16*)  alloc((size_t)G4 * DD * 2);
    u16*   whs  = (u16*)  alloc((size_t)G4 * HH * 2);
    u16*   wxp  = (u16*)  alloc((size_t)G4 * DD * 2);
    u16*   whp  = (u16*)  alloc((size_t)G4 * HH * 2);
    float* bs   = (float*)alloc((size_t)G4 * 4);
    float* bp   = (float*)alloc((size_t)G4 * 4);
    u16*   fsw  = (u16*)  alloc((size_t)DD * HH * 2);
    u16*   pfc  = (u16*)  alloc((size_t)2 * DD * HH * 2);
    u16*   hs0  = (u16*)  alloc((size_t)BB * HH * 2);
    u16*   hs1  = (u16*)  alloc((size_t)BB * HH * 2);
    u16*   hp0  = (u16*)  alloc((size_t)BB * HH * 2);
    u16*   hp1  = (u16*)  alloc((size_t)BB * HH * 2);
    float* cs   = (float*)alloc((size_t)BB * HH * 4);
    float* cp   = (float*)alloc((size_t)BB * HH * 4);
    u16*   inp  = (u16*)  alloc((size_t)BB * DD * 2);
    u16*   xin  = (u16*)  alloc((size_t)BB * DD * 2);
    float* mbuf = (float*)alloc((size_t)BB * DD * 4);

    // --- one-time (per call) weight conversion / reordering ---
    {
        int n;
        n = G4 * DD;      k_cvt_gates<<<dim3((n + 255) / 256), 256, 0, stream>>>(s_x2h_w, wxs, 7, n);
        n = G4 * HH;      k_cvt_gates<<<dim3((n + 255) / 256), 256, 0, stream>>>(s_h2h_w, whs, 10, n);
        n = G4 * DD;      k_cvt_gates<<<dim3((n + 255) / 256), 256, 0, stream>>>(p_x2h_w, wxp, 7, n);
        n = G4 * HH;      k_cvt_gates<<<dim3((n + 255) / 256), 256, 0, stream>>>(p_h2h_w, whp, 10, n);
        k_bias2<<<dim3(G4 / 256), 256, 0, stream>>>(s_x2h_b, s_h2h_b, bs);
        k_bias2<<<dim3(G4 / 256), 256, 0, stream>>>(p_x2h_b, p_h2h_b, bp);
        n = DD * HH;      k_cvt<<<dim3((n + 255) / 256), 256, 0, stream>>>(fs_w, fsw, n);
        n = 2 * DD * HH;  k_cvt<<<dim3((n + 255) / 256), 256, 0, stream>>>(p_fc_w, pfc, n);
        n = BB * HH;      k_init<<<dim3((n + 255) / 256), 256, 0, stream>>>(x, inp, hs0, hp0, cs, cp);
    }

    // --- the scan ---
    for (int t = 0; t < TOUT; ++t) {
        const u16* hs_r = (t & 1) ? hs1 : hs0;
        u16*       hs_w = (t & 1) ? hs0 : hs1;
        const u16* hp_r = (t & 1) ? hp1 : hp0;
        u16*       hp_w = (t & 1) ? hp0 : hp1;

        k_lstm<<<dim3(G4 / 64, BB / 64), 256, 0, stream>>>(inp, hs_r, wxs, whs, bs, cs, hs_w);
        k_mu<<<dim3(DD / 64, BB / 64), 256, 0, stream>>>(hs_w, fsw, fs_b, x, t,
                                                         o_mask, o_reg, o_mu, o_prob, o_z, xin, mbuf);
        k_lstm<<<dim3(G4 / 64, BB / 64), 256, 0, stream>>>(xin, hp_r, wxp, whp, bp, cp, hp_w);
        k_fc<<<dim3(2 * DD / 64, BB / 64), 256, 0, stream>>>(hp_w, pfc, p_fc_b, x, t, mbuf,
                                                             o_x0, o_x1, inp);
    }
}